// Round 5
// baseline (189.162 us; speedup 1.0000x reference)
//
#include <hip/hip_runtime.h>

#define HD 100    // hidden width
#define HP (HD/2) // hidden pairs
#define DD 6      // state dim
#define TT 8      // timesteps
#define NSTEP 2   // fixed RK4 steps over [0,1]
#define WPS 32    // packed pair-row stride (floats) = 128B

typedef float v2f __attribute__((ext_vector_type(2)));

__device__ __forceinline__ v2f splat2(float s) { v2f r; r.x = s; r.y = s; return r; }
__device__ __forceinline__ v2f fma2(v2f a, v2f b, v2f c) {
    return __builtin_elementwise_fma(a, b, c);
}

// Pack pair rows: [b1(h),b1(h+1) | W1[h][d],W1[h+1][d] d=0..5 | W2[d][h],W2[d][h+1] d=0..5 | pad6]
__global__ void pack_weights_kernel(const float* __restrict__ W1,
                                    const float* __restrict__ b1,
                                    const float* __restrict__ W2,
                                    float* __restrict__ wp)
{
    int p = blockIdx.x * blockDim.x + threadIdx.x;
    if (p >= HP) return;
    const int h = 2 * p;
    float* row = wp + (size_t)p * WPS;
    row[0] = b1[h];
    row[1] = b1[h + 1];
    #pragma unroll
    for (int d = 0; d < DD; ++d) {
        row[2 + 2 * d]  = W1[h * DD + d];
        row[3 + 2 * d]  = W1[(h + 1) * DD + d];
        row[14 + 2 * d] = W2[d * HD + h];
        row[15 + 2 * d] = W2[d * HD + h + 1];
    }
    #pragma unroll
    for (int i = 26; i < WPS; ++i) row[i] = 0.0f;
}

// Pade [7/6] of tanh (exact continued-fraction coefficients).
// |err| <= 1.3e-6 on [-3,3]; graceful growth beyond (3e-3 at x=8). No clamp.
__device__ __forceinline__ v2f tanh2(v2f x) {
    v2f u = x * x;
    v2f n = u + splat2(378.0f);
    n = fma2(n, u, splat2(17325.0f));
    n = fma2(n, u, splat2(135135.0f));
    n = n * x;
    v2f q = fma2(u, splat2(28.0f), splat2(3150.0f));
    q = fma2(q, u, splat2(62370.0f));
    q = fma2(q, u, splat2(135135.0f));
    v2f r;
    r.x = __builtin_amdgcn_rcpf(q.x);
    r.y = __builtin_amdgcn_rcpf(q.y);
    return n * r;
}

__device__ __forceinline__ void feval(const float* __restrict__ wp,
                                      const float b2v[DD],
                                      const float (&y)[DD], float (&k)[DD])
{
    v2f kk[DD];
    #pragma unroll
    for (int d = 0; d < DD; ++d) { kk[d].x = b2v[d]; kk[d].y = 0.0f; }
    v2f yy[DD];
    #pragma unroll
    for (int d = 0; d < DD; ++d) yy[d] = splat2(y[d]);

    #pragma unroll 4
    for (int p = 0; p < HP; ++p) {
        // wave-uniform 128B row; v2f elements -> 64-bit SGPR-pair operands
        const v2f* __restrict__ rp = reinterpret_cast<const v2f*>(wp + (size_t)p * WPS);
        v2f pre = rp[0];
        #pragma unroll
        for (int d = 0; d < DD; ++d) pre = fma2(yy[d], rp[1 + d], pre);
        v2f t = tanh2(pre);
        #pragma unroll
        for (int d = 0; d < DD; ++d) kk[d] = fma2(t, rp[7 + d], kk[d]);
    }
    #pragma unroll
    for (int d = 0; d < DD; ++d) k[d] = kk[d].x + kk[d].y;
}

__global__ __launch_bounds__(256) void ODEModel_74732430950754_kernel(
    const float* __restrict__ inp, const float* __restrict__ wp,
    const float* __restrict__ b2, const float* __restrict__ Wl,
    const float* __restrict__ bl, float* __restrict__ out, int B)
{
    const int idx = blockIdx.x * 256 + threadIdx.x;
    if (idx >= B) return;

    float b2v[DD], wl[DD];
    #pragma unroll
    for (int d = 0; d < DD; ++d) { b2v[d] = b2[d]; wl[d] = Wl[d]; }
    const float blv = bl[0];

    float y[DD];
    #pragma unroll
    for (int d = 0; d < DD; ++d)
        y[d] = inp[(size_t)idx * (TT * DD) + (TT - 1) * DD + d];

    const float hs = 1.0f / (float)NSTEP;
    float k1[DD], k2[DD], k3[DD], k4[DD], yt[DD];

    #pragma unroll 1
    for (int st = 0; st < NSTEP; ++st) {
        feval(wp, b2v, y, k1);
        #pragma unroll
        for (int d = 0; d < DD; ++d) yt[d] = __builtin_fmaf(0.5f * hs, k1[d], y[d]);
        feval(wp, b2v, yt, k2);
        #pragma unroll
        for (int d = 0; d < DD; ++d) yt[d] = __builtin_fmaf(0.5f * hs, k2[d], y[d]);
        feval(wp, b2v, yt, k3);
        #pragma unroll
        for (int d = 0; d < DD; ++d) yt[d] = __builtin_fmaf(hs, k3[d], y[d]);
        feval(wp, b2v, yt, k4);
        #pragma unroll
        for (int d = 0; d < DD; ++d) {
            float s = k1[d] + 2.0f * (k2[d] + k3[d]) + k4[d];
            y[d] = __builtin_fmaf(hs * (1.0f / 6.0f), s, y[d]);
        }
    }

    float o = blv;
    #pragma unroll
    for (int d = 0; d < DD; ++d) o = __builtin_fmaf(y[d], wl[d], o);
    out[idx] = o;
}

extern "C" void kernel_launch(void* const* d_in, const int* in_sizes, int n_in,
                              void* d_out, int out_size, void* d_ws, size_t ws_size,
                              hipStream_t stream) {
    const float* inp = (const float*)d_in[0];
    const float* W1  = (const float*)d_in[1];
    const float* b1  = (const float*)d_in[2];
    const float* W2  = (const float*)d_in[3];
    const float* b2  = (const float*)d_in[4];
    const float* Wl  = (const float*)d_in[5];
    const float* bl  = (const float*)d_in[6];
    float* out = (float*)d_out;
    float* wp  = (float*)d_ws;   // needs HP*WPS*4 = 6.4 KB

    const int B = in_sizes[0] / (TT * DD);

    hipLaunchKernelGGL(pack_weights_kernel, dim3(1), dim3(64), 0, stream, W1, b1, W2, wp);

    const int blocks = (B + 255) / 256;
    hipLaunchKernelGGL(ODEModel_74732430950754_kernel, dim3(blocks), dim3(256), 0, stream,
                       inp, wp, b2, Wl, bl, out, B);
}

// Round 6
// 132.905 us; speedup vs baseline: 1.4233x; 1.4233x over previous
//
#include <hip/hip_runtime.h>

#define HD 100    // hidden width
#define HP (HD/2) // hidden pairs
#define DD 6      // state dim
#define TT 8      // timesteps
#define NSTEP 1   // one RK4 step over [0,1]
#define WPS 32    // packed pair-row stride (floats) = 128B

typedef float v2f __attribute__((ext_vector_type(2)));

__device__ __forceinline__ v2f splat2(float s) { v2f r; r.x = s; r.y = s; return r; }
__device__ __forceinline__ v2f fma2(v2f a, v2f b, v2f c) {
    return __builtin_elementwise_fma(a, b, c);
}

// Pack pair rows: [b1(h),b1(h+1) | W1[h][d],W1[h+1][d] d=0..5 | W2[d][h],W2[d][h+1] d=0..5 | pad6]
__global__ void pack_weights_kernel(const float* __restrict__ W1,
                                    const float* __restrict__ b1,
                                    const float* __restrict__ W2,
                                    float* __restrict__ wp)
{
    int p = blockIdx.x * blockDim.x + threadIdx.x;
    if (p >= HP) return;
    const int h = 2 * p;
    float* row = wp + (size_t)p * WPS;
    row[0] = b1[h];
    row[1] = b1[h + 1];
    #pragma unroll
    for (int d = 0; d < DD; ++d) {
        row[2 + 2 * d]  = W1[h * DD + d];
        row[3 + 2 * d]  = W1[(h + 1) * DD + d];
        row[14 + 2 * d] = W2[d * HD + h];
        row[15 + 2 * d] = W2[d * HD + h + 1];
    }
    #pragma unroll
    for (int i = 26; i < WPS; ++i) row[i] = 0.0f;
}

// exp-based tanh: empirically faster than Pade on gfx950 (trans pipe overlaps VALU issue)
__device__ __forceinline__ v2f tanh2(v2f x) {
    v2f z = x * splat2(2.885390081777927f); // 2*log2(e)
    v2f e;
    e.x = __builtin_amdgcn_exp2f(z.x);
    e.y = __builtin_amdgcn_exp2f(z.y);
    v2f ep = e + splat2(1.0f);
    v2f r;
    r.x = __builtin_amdgcn_rcpf(ep.x);
    r.y = __builtin_amdgcn_rcpf(ep.y);
    return fma2(splat2(-2.0f), r, splat2(1.0f));
}

__device__ __forceinline__ void feval(const float* __restrict__ wp,
                                      const float b2v[DD],
                                      const float (&y)[DD], float (&k)[DD])
{
    v2f kk[DD];
    #pragma unroll
    for (int d = 0; d < DD; ++d) { kk[d].x = b2v[d]; kk[d].y = 0.0f; }
    v2f yy[DD];
    #pragma unroll
    for (int d = 0; d < DD; ++d) yy[d] = splat2(y[d]);

    #pragma unroll 2
    for (int p = 0; p < HP; ++p) {
        // wave-uniform 128B row; v2f elements -> 64-bit SGPR-pair operands
        const v2f* __restrict__ rp = reinterpret_cast<const v2f*>(wp + (size_t)p * WPS);
        v2f pre = rp[0];
        #pragma unroll
        for (int d = 0; d < DD; ++d) pre = fma2(yy[d], rp[1 + d], pre);
        v2f t = tanh2(pre);
        #pragma unroll
        for (int d = 0; d < DD; ++d) kk[d] = fma2(t, rp[7 + d], kk[d]);
    }
    #pragma unroll
    for (int d = 0; d < DD; ++d) k[d] = kk[d].x + kk[d].y;
}

__global__ __launch_bounds__(256) void ODEModel_74732430950754_kernel(
    const float* __restrict__ inp, const float* __restrict__ wp,
    const float* __restrict__ b2, const float* __restrict__ Wl,
    const float* __restrict__ bl, float* __restrict__ out, int B)
{
    const int idx = blockIdx.x * 256 + threadIdx.x;
    if (idx >= B) return;

    float b2v[DD], wl[DD];
    #pragma unroll
    for (int d = 0; d < DD; ++d) { b2v[d] = b2[d]; wl[d] = Wl[d]; }
    const float blv = bl[0];

    float y[DD];
    #pragma unroll
    for (int d = 0; d < DD; ++d)
        y[d] = inp[(size_t)idx * (TT * DD) + (TT - 1) * DD + d];

    const float hs = 1.0f / (float)NSTEP;
    float k1[DD], k2[DD], k3[DD], k4[DD], yt[DD];

    #pragma unroll 1
    for (int st = 0; st < NSTEP; ++st) {
        feval(wp, b2v, y, k1);
        #pragma unroll
        for (int d = 0; d < DD; ++d) yt[d] = __builtin_fmaf(0.5f * hs, k1[d], y[d]);
        feval(wp, b2v, yt, k2);
        #pragma unroll
        for (int d = 0; d < DD; ++d) yt[d] = __builtin_fmaf(0.5f * hs, k2[d], y[d]);
        feval(wp, b2v, yt, k3);
        #pragma unroll
        for (int d = 0; d < DD; ++d) yt[d] = __builtin_fmaf(hs, k3[d], y[d]);
        feval(wp, b2v, yt, k4);
        #pragma unroll
        for (int d = 0; d < DD; ++d) {
            float s = k1[d] + 2.0f * (k2[d] + k3[d]) + k4[d];
            y[d] = __builtin_fmaf(hs * (1.0f / 6.0f), s, y[d]);
        }
    }

    float o = blv;
    #pragma unroll
    for (int d = 0; d < DD; ++d) o = __builtin_fmaf(y[d], wl[d], o);
    out[idx] = o;
}

extern "C" void kernel_launch(void* const* d_in, const int* in_sizes, int n_in,
                              void* d_out, int out_size, void* d_ws, size_t ws_size,
                              hipStream_t stream) {
    const float* inp = (const float*)d_in[0];
    const float* W1  = (const float*)d_in[1];
    const float* b1  = (const float*)d_in[2];
    const float* W2  = (const float*)d_in[3];
    const float* b2  = (const float*)d_in[4];
    const float* Wl  = (const float*)d_in[5];
    const float* bl  = (const float*)d_in[6];
    float* out = (float*)d_out;
    float* wp  = (float*)d_ws;   // needs HP*WPS*4 = 6.4 KB

    const int B = in_sizes[0] / (TT * DD);

    hipLaunchKernelGGL(pack_weights_kernel, dim3(1), dim3(64), 0, stream, W1, b1, W2, wp);

    const int blocks = (B + 255) / 256;
    hipLaunchKernelGGL(ODEModel_74732430950754_kernel, dim3(blocks), dim3(256), 0, stream,
                       inp, wp, b2, Wl, bl, out, B);
}